// Round 1
// baseline (374.056 us; speedup 1.0000x reference)
//
#include <hip/hip_runtime.h>
#include <math.h>

#define NN 512
#define CSd 384
#define Hh 12
#define CATd 2112

// ---------------- Kernel 1: projections + point rotation ----------------
// grid 128 blocks, 256 threads; each block handles 4 residues.
__global__ void k_proj(const float* __restrict__ s,
                       const float* __restrict__ rot,
                       const float* __restrict__ trans,
                       const float* __restrict__ w_q, const float* __restrict__ b_q,
                       const float* __restrict__ w_kv, const float* __restrict__ b_kv,
                       const float* __restrict__ w_qp, const float* __restrict__ b_qp,
                       const float* __restrict__ w_kvp, const float* __restrict__ b_kvp,
                       float* __restrict__ q, float* __restrict__ k, float* __restrict__ v,
                       float* __restrict__ qp, float* __restrict__ kp, float* __restrict__ vp)
{
  __shared__ float sL[4][CSd];     // 6 KB
  __shared__ float praw[4][576];   // 9.2 KB: [0..143]=q_pts raw, [144..575]=kv_pts raw
  const int i0 = blockIdx.x * 4;
  const int t  = threadIdx.x;

  for (int u = t; u < 4 * CSd; u += 256) sL[u / CSd][u % CSd] = s[i0 * CSd + u];
  __syncthreads();

  // q = s @ w_q + b_q   (192 cols)
  for (int c = t; c < 192; c += 256) {
    float a0 = b_q[c], a1 = a0, a2 = a0, a3 = a0;
    for (int kk = 0; kk < CSd; kk++) {
      float w = w_q[kk * 192 + c];
      a0 += sL[0][kk] * w; a1 += sL[1][kk] * w; a2 += sL[2][kk] * w; a3 += sL[3][kk] * w;
    }
    q[(i0 + 0) * 192 + c] = a0; q[(i0 + 1) * 192 + c] = a1;
    q[(i0 + 2) * 192 + c] = a2; q[(i0 + 3) * 192 + c] = a3;
  }
  // kv = s @ w_kv + b_kv (384 cols) -> split into k, v
  for (int c = t; c < 384; c += 256) {
    float a0 = b_kv[c], a1 = a0, a2 = a0, a3 = a0;
    for (int kk = 0; kk < CSd; kk++) {
      float w = w_kv[kk * 384 + c];
      a0 += sL[0][kk] * w; a1 += sL[1][kk] * w; a2 += sL[2][kk] * w; a3 += sL[3][kk] * w;
    }
    int h = c >> 5, cc = c & 31;
    float* dst = (cc < 16) ? k : v;
    int col = h * 16 + (cc & 15);
    dst[(i0 + 0) * 192 + col] = a0; dst[(i0 + 1) * 192 + col] = a1;
    dst[(i0 + 2) * 192 + col] = a2; dst[(i0 + 3) * 192 + col] = a3;
  }
  // q_pts raw (144 cols)
  for (int c = t; c < 144; c += 256) {
    float a0 = b_qp[c], a1 = a0, a2 = a0, a3 = a0;
    for (int kk = 0; kk < CSd; kk++) {
      float w = w_qp[kk * 144 + c];
      a0 += sL[0][kk] * w; a1 += sL[1][kk] * w; a2 += sL[2][kk] * w; a3 += sL[3][kk] * w;
    }
    praw[0][c] = a0; praw[1][c] = a1; praw[2][c] = a2; praw[3][c] = a3;
  }
  // kv_pts raw (432 cols)
  for (int c = t; c < 432; c += 256) {
    float a0 = b_kvp[c], a1 = a0, a2 = a0, a3 = a0;
    for (int kk = 0; kk < CSd; kk++) {
      float w = w_kvp[kk * 432 + c];
      a0 += sL[0][kk] * w; a1 += sL[1][kk] * w; a2 += sL[2][kk] * w; a3 += sL[3][kk] * w;
    }
    praw[0][144 + c] = a0; praw[1][144 + c] = a1;
    praw[2][144 + c] = a2; praw[3][144 + c] = a3;
  }
  __syncthreads();

  // rotate all points: 4 rows * (48 q-pts + 144 kv-pts) = 768 tasks
  for (int task = t; task < 768; task += 256) {
    int r = task / 192, pidx = task % 192;
    int i = i0 + r;
    float x, y, zz;
    if (pidx < 48) { x = praw[r][pidx]; y = praw[r][48 + pidx]; zz = praw[r][96 + pidx]; }
    else { int idx = pidx - 48; x = praw[r][144 + idx]; y = praw[r][288 + idx]; zz = praw[r][432 + idx]; }
    const float* Rm = rot + i * 9;
    const float* tr = trans + i * 3;
    float rx = Rm[0] * x + Rm[1] * y + Rm[2] * zz + tr[0];
    float ry = Rm[3] * x + Rm[4] * y + Rm[5] * zz + tr[1];
    float rz = Rm[6] * x + Rm[7] * y + Rm[8] * zz + tr[2];
    if (pidx < 48) {
      float* d = qp + ((size_t)i * 48 + pidx) * 3;
      d[0] = rx; d[1] = ry; d[2] = rz;
    } else {
      int idx = pidx - 48, h = idx / 12, pp = idx % 12;
      if (pp < 4) { float* d = kp + ((size_t)i * 48 + h * 4 + pp) * 3; d[0] = rx; d[1] = ry; d[2] = rz; }
      else        { float* d = vp + ((size_t)i * 96 + h * 8 + pp - 4) * 3; d[0] = rx; d[1] = ry; d[2] = rz; }
    }
  }
}

// ---------------- Kernel 2: bias = z @ w_b, scaled + mask, into logits ----------------
// grid 4096 (64 (i,j)-rows each), 256 threads
__global__ void k_bias(const float* __restrict__ z, const float* __restrict__ w_b,
                       const float* __restrict__ b_b, const float* __restrict__ mask,
                       float* __restrict__ a)
{
  __shared__ float zL[64][129];   // +1 pad: (r+c)%32 banks
  __shared__ float wbL[128 * 12];
  const int t = threadIdx.x;
  const int row0 = blockIdx.x * 64;         // flat (i*512 + j)
  const int i = row0 >> 9;
  const int j0 = row0 & 511;

  for (int u = t; u < 1536; u += 256) wbL[u] = w_b[u];
  for (int u = t; u < 64 * 128; u += 256) zL[u >> 7][u & 127] = z[(size_t)row0 * 128 + u];
  __syncthreads();

  const int r = t & 63, hb = t >> 6;
  const float mi = mask[i], mj = mask[j0 + r];
  const float mterm = 100000.0f * (mi * mj - 1.0f);
  const float W_L = 0.57735026919f;
  const float* zr = zL[r];
  for (int hh = hb; hh < 12; hh += 4) {
    float acc = b_b[hh];
    for (int c = 0; c < 128; c++) acc += zr[c] * wbL[c * 12 + hh];
    a[((size_t)hh * NN + i) * NN + j0 + r] = W_L * acc + mterm;
  }
}

// ---------------- Kernel 3: qk + point-attention + softmax ----------------
// grid (512, 12), 256 threads; block = one (i, h) row of 512 logits
__global__ void k_attn(const float* __restrict__ q, const float* __restrict__ k,
                       const float* __restrict__ qp, const float* __restrict__ kp,
                       const float* __restrict__ hws, float* __restrict__ a)
{
  const int i = blockIdx.x, h = blockIdx.y, t = threadIdx.x;
  __shared__ float qL[16], qpL[12];
  __shared__ float red[2][4];
  if (t < 16) qL[t] = q[i * 192 + h * 16 + t];
  else if (t >= 32 && t < 44) qpL[t - 32] = qp[((size_t)i * 48 + h * 4) * 3 + (t - 32)];
  __syncthreads();

  const float hwv = 0.13608276348f * log1pf(expf(hws[h]));  // softplus * w_p
  const float W_C = 0.14433756730f;                          // sqrt(1/48)
  const size_t base = ((size_t)h * NN + i) * NN;

  float lg[2];
  for (int u = 0; u < 2; u++) {
    int j = t + u * 256;
    float acc = a[base + j];
    const float* kr = k + (size_t)j * 192 + h * 16;
    float dot = 0.f;
    for (int c = 0; c < 16; c++) dot += qL[c] * kr[c];
    const float* kpr = kp + ((size_t)j * 48 + h * 4) * 3;
    float d2 = 0.f;
    for (int p = 0; p < 4; p++) {
      float dx = qpL[p * 3 + 0] - kpr[p * 3 + 0];
      float dy = qpL[p * 3 + 1] - kpr[p * 3 + 1];
      float dz = qpL[p * 3 + 2] - kpr[p * 3 + 2];
      d2 += dx * dx + dy * dy + dz * dz;
    }
    lg[u] = acc + W_C * dot - 0.5f * hwv * d2;
  }

  float m = fmaxf(lg[0], lg[1]);
  for (int o = 1; o < 64; o <<= 1) m = fmaxf(m, __shfl_xor(m, o));
  if ((t & 63) == 0) red[0][t >> 6] = m;
  __syncthreads();
  m = fmaxf(fmaxf(red[0][0], red[0][1]), fmaxf(red[0][2], red[0][3]));
  float e0 = expf(lg[0] - m), e1 = expf(lg[1] - m);
  float sm = e0 + e1;
  for (int o = 1; o < 64; o <<= 1) sm += __shfl_xor(sm, o);
  if ((t & 63) == 0) red[1][t >> 6] = sm;
  __syncthreads();
  float inv = 1.0f / (red[1][0] + red[1][1] + red[1][2] + red[1][3]);
  a[base + t]       = e0 * inv;
  a[base + t + 256] = e1 * inv;
}

// ---------------- Kernel 4: o, o_pt (+inv rot, norm), o_pair -> cat ----------------
// grid 512 (one per i), 512 threads
__global__ void k_out(const float* __restrict__ a, const float* __restrict__ v,
                      const float* __restrict__ vp, const float* __restrict__ z,
                      const float* __restrict__ rot, const float* __restrict__ trans,
                      float* __restrict__ cat)
{
  __shared__ float aL[12][513];
  __shared__ float optL[12][8][3];
  const int i = blockIdx.x, t = threadIdx.x;
  for (int u = t; u < 12 * 512; u += 512)
    aL[u >> 9][u & 511] = a[((size_t)(u >> 9) * NN + i) * NN + (u & 511)];
  __syncthreads();

  if (t < 192) {                       // o[h][c], col = t
    float acc = 0.f;
    const int h = t >> 4;
    for (int j = 0; j < 512; j++) acc += aL[h][j] * v[(size_t)j * 192 + t];
    cat[(size_t)i * CATd + t] = acc;
  } else if (t < 480) {                // o_pt[h][p][x], flat u = t-192
    int u = t - 192, h = u / 24;
    float acc = 0.f;
    for (int j = 0; j < 512; j++) acc += aL[h][j] * vp[(size_t)j * 288 + u];
    int pc = u % 24;
    optL[h][pc / 3][pc % 3] = acc;
  }
  __syncthreads();

  if (t < 96) {                        // inverse rotation + norm
    int h = t >> 3, p = t & 7;
    const float* Rm = rot + i * 9;
    const float* tr = trans + i * 3;
    float ox = optL[h][p][0] - tr[0];
    float oy = optL[h][p][1] - tr[1];
    float oz = optL[h][p][2] - tr[2];
    float rx = Rm[0] * ox + Rm[3] * oy + Rm[6] * oz;   // R^T
    float ry = Rm[1] * ox + Rm[4] * oy + Rm[7] * oz;
    float rz = Rm[2] * ox + Rm[5] * oy + Rm[8] * oz;
    float nrm = sqrtf(rx * rx + ry * ry + rz * rz + 1e-8f);
    size_t b = (size_t)i * CATd;
    cat[b + 192 + t] = rx; cat[b + 288 + t] = ry;
    cat[b + 384 + t] = rz; cat[b + 480 + t] = nrm;
  }

  // o_pair: 12*128 outputs, 3 per thread
  const int c = t & 127, hb = t >> 7;   // hb in 0..3
  float a0 = 0.f, a1 = 0.f, a2 = 0.f;
  const float* zr = z + (size_t)i * 512 * 128 + c;
  for (int j = 0; j < 512; j++) {
    float zv = zr[(size_t)j * 128];
    a0 += aL[hb][j] * zv; a1 += aL[hb + 4][j] * zv; a2 += aL[hb + 8][j] * zv;
  }
  size_t b = (size_t)i * CATd + 576;
  cat[b + hb * 128 + c] = a0;
  cat[b + (hb + 4) * 128 + c] = a1;
  cat[b + (hb + 8) * 128 + c] = a2;
}

// ---------------- Kernel 5: out = cat @ w_out + b_out ----------------
// grid 128 (4 rows each), 384 threads (one per output col)
__global__ void k_final(const float* __restrict__ cat, const float* __restrict__ w_out,
                        const float* __restrict__ b_out, float* __restrict__ out)
{
  __shared__ float catL[4 * CATd];   // 33.8 KB
  const int i0 = blockIdx.x * 4, t = threadIdx.x;
  for (int u = t; u < 4 * CATd; u += 384) catL[u] = cat[(size_t)i0 * CATd + u];
  __syncthreads();
  float a0 = b_out[t], a1 = a0, a2 = a0, a3 = a0;
  for (int kk = 0; kk < CATd; kk++) {
    float w = w_out[kk * 384 + t];
    a0 += catL[kk] * w;
    a1 += catL[CATd + kk] * w;
    a2 += catL[2 * CATd + kk] * w;
    a3 += catL[3 * CATd + kk] * w;
  }
  out[(i0 + 0) * 384 + t] = a0;
  out[(i0 + 1) * 384 + t] = a1;
  out[(i0 + 2) * 384 + t] = a2;
  out[(i0 + 3) * 384 + t] = a3;
}

extern "C" void kernel_launch(void* const* d_in, const int* in_sizes, int n_in,
                              void* d_out, int out_size, void* d_ws, size_t ws_size,
                              hipStream_t stream) {
  const float* s      = (const float*)d_in[0];
  const float* z      = (const float*)d_in[1];
  const float* rot    = (const float*)d_in[2];
  const float* trans  = (const float*)d_in[3];
  const float* mask   = (const float*)d_in[4];
  const float* w_q    = (const float*)d_in[5];
  const float* b_q    = (const float*)d_in[6];
  const float* w_kv   = (const float*)d_in[7];
  const float* b_kv   = (const float*)d_in[8];
  const float* w_qp   = (const float*)d_in[9];
  const float* b_qp   = (const float*)d_in[10];
  const float* w_kvp  = (const float*)d_in[11];
  const float* b_kvp  = (const float*)d_in[12];
  const float* w_b    = (const float*)d_in[13];
  const float* b_b    = (const float*)d_in[14];
  const float* hws    = (const float*)d_in[15];
  const float* w_out  = (const float*)d_in[16];
  const float* b_out  = (const float*)d_in[17];
  float* out = (float*)d_out;

  float* ws  = (float*)d_ws;
  float* q   = ws;                 // 512*192
  float* k   = q  + 98304;         // 512*192
  float* v   = k  + 98304;         // 512*192
  float* qp  = v  + 98304;         // 512*48*3
  float* kp  = qp + 73728;         // 512*48*3
  float* vp  = kp + 73728;         // 512*96*3
  float* a   = vp + 147456;        // 12*512*512
  float* cat = a  + 3145728;       // 512*2112

  k_proj<<<128, 256, 0, stream>>>(s, rot, trans, w_q, b_q, w_kv, b_kv,
                                  w_qp, b_qp, w_kvp, b_kvp, q, k, v, qp, kp, vp);
  k_bias<<<4096, 256, 0, stream>>>(z, w_b, b_b, mask, a);
  k_attn<<<dim3(512, 12), 256, 0, stream>>>(q, k, qp, kp, hws, a);
  k_out<<<512, 512, 0, stream>>>(a, v, vp, z, rot, trans, cat);
  k_final<<<128, 384, 0, stream>>>(cat, w_out, b_out, out);
}

// Round 2
// 314.915 us; speedup vs baseline: 1.1878x; 1.1878x over previous
//
#include <hip/hip_runtime.h>
#include <math.h>

#define NN 512
#define CSd 384
#define Hh 12
#define CATd 2112

// ---------------- Kernel 1a: fused projection GEMM ----------------
// proj[512][1152] = s[512][384] @ [w_q | w_kv | w_qp | w_kvp] + bias
// grid (16,18): 32-row x 64-col tiles; 256 threads; thread = 8 rows x 1 col.
__global__ void k_projgemm(const float* __restrict__ s,
                           const float* __restrict__ w_q, const float* __restrict__ b_q,
                           const float* __restrict__ w_kv, const float* __restrict__ b_kv,
                           const float* __restrict__ w_qp, const float* __restrict__ b_qp,
                           const float* __restrict__ w_kvp, const float* __restrict__ b_kvp,
                           float* __restrict__ proj)
{
  __shared__ float sT[384 * 40];          // s-tile transposed, pad 40 (61.4 KB)
  const int t  = threadIdx.x;
  const int i0 = blockIdx.x * 32;         // row tile
  const int c0 = blockIdx.y * 64;         // col tile (virtual concat space)

  // stage: sT[col][row] = s[i0+row][col]; waves stay within one row (384=6*64)
  for (int u = t; u < 32 * 384; u += 256) {
    int row = u / 384, col = u % 384;
    sT[col * 40 + row] = s[(i0 + row) * CSd + col];
  }
  __syncthreads();

  const int c    = t & 63;                // col within tile
  const int rgrp = t >> 6;                // 0..3 -> rows rgrp*8..+7
  const int gc   = c0 + c;                // global virtual col

  const float* wp;
  int stride;
  float bias;
  if (gc < 192)      { wp = w_q   + gc;         stride = 192; bias = b_q[gc]; }
  else if (gc < 576) { wp = w_kv  + (gc - 192); stride = 384; bias = b_kv[gc - 192]; }
  else if (gc < 720) { wp = w_qp  + (gc - 576); stride = 144; bias = b_qp[gc - 576]; }
  else               { wp = w_kvp + (gc - 720); stride = 432; bias = b_kvp[gc - 720]; }

  float acc[8];
#pragma unroll
  for (int j = 0; j < 8; j++) acc[j] = bias;

  const int r0 = rgrp * 8;
#pragma unroll 4
  for (int kk = 0; kk < 384; kk++) {
    float wv = *wp; wp += stride;
    const float4 a0 = *reinterpret_cast<const float4*>(&sT[kk * 40 + r0]);
    const float4 a1 = *reinterpret_cast<const float4*>(&sT[kk * 40 + r0 + 4]);
    acc[0] += a0.x * wv; acc[1] += a0.y * wv; acc[2] += a0.z * wv; acc[3] += a0.w * wv;
    acc[4] += a1.x * wv; acc[5] += a1.y * wv; acc[6] += a1.z * wv; acc[7] += a1.w * wv;
  }
#pragma unroll
  for (int j = 0; j < 8; j++)
    proj[(size_t)(i0 + r0 + j) * 1152 + gc] = acc[j];
}

// ---------------- Kernel 1b: scatter q/k/v + rotate points ----------------
// grid 512 (one residue each), 256 threads
__global__ void k_rot(const float* __restrict__ proj,
                      const float* __restrict__ rot, const float* __restrict__ trans,
                      float* __restrict__ q, float* __restrict__ k, float* __restrict__ v,
                      float* __restrict__ qp, float* __restrict__ kp, float* __restrict__ vp)
{
  __shared__ float ptsL[576];
  const int i = blockIdx.x, t = threadIdx.x;
  const float* pr = proj + (size_t)i * 1152;

  for (int u = t; u < 576; u += 256) ptsL[u] = pr[576 + u];

  // q / k / v scatter (cols 0..575)
  for (int cI = t; cI < 576; cI += 256) {
    float pv = pr[cI];
    if (cI < 192) q[i * 192 + cI] = pv;
    else {
      int local = cI - 192, h = local >> 5, cc = local & 31;
      if (cc < 16) k[i * 192 + h * 16 + cc] = pv;
      else         v[i * 192 + h * 16 + cc - 16] = pv;
    }
  }
  __syncthreads();

  // rotate 192 points
  for (int p = t; p < 192; p += 256) {
    float x, y, zz;
    if (p < 48) { x = ptsL[p]; y = ptsL[48 + p]; zz = ptsL[96 + p]; }
    else { int idx = p - 48; x = ptsL[144 + idx]; y = ptsL[288 + idx]; zz = ptsL[432 + idx]; }
    const float* Rm = rot + i * 9;
    const float* tr = trans + i * 3;
    float rx = Rm[0] * x + Rm[1] * y + Rm[2] * zz + tr[0];
    float ry = Rm[3] * x + Rm[4] * y + Rm[5] * zz + tr[1];
    float rz = Rm[6] * x + Rm[7] * y + Rm[8] * zz + tr[2];
    if (p < 48) {
      float* d = qp + ((size_t)i * 48 + p) * 3;
      d[0] = rx; d[1] = ry; d[2] = rz;
    } else {
      int idx = p - 48, h = idx / 12, pp = idx % 12;
      if (pp < 4) { float* d = kp + ((size_t)i * 48 + h * 4 + pp) * 3; d[0] = rx; d[1] = ry; d[2] = rz; }
      else        { float* d = vp + ((size_t)i * 96 + h * 8 + pp - 4) * 3; d[0] = rx; d[1] = ry; d[2] = rz; }
    }
  }
}

// ---------------- Kernel 2: bias = z @ w_b, scaled + mask, into logits ----------------
__global__ void k_bias(const float* __restrict__ z, const float* __restrict__ w_b,
                       const float* __restrict__ b_b, const float* __restrict__ mask,
                       float* __restrict__ a)
{
  __shared__ float zL[64][129];
  __shared__ float wbL[128 * 12];
  const int t = threadIdx.x;
  const int row0 = blockIdx.x * 64;
  const int i = row0 >> 9;
  const int j0 = row0 & 511;

  for (int u = t; u < 1536; u += 256) wbL[u] = w_b[u];
  for (int u = t; u < 64 * 128; u += 256) zL[u >> 7][u & 127] = z[(size_t)row0 * 128 + u];
  __syncthreads();

  const int r = t & 63, hb = t >> 6;
  const float mi = mask[i], mj = mask[j0 + r];
  const float mterm = 100000.0f * (mi * mj - 1.0f);
  const float W_L = 0.57735026919f;
  const float* zr = zL[r];
  for (int hh = hb; hh < 12; hh += 4) {
    float acc = b_b[hh];
    for (int c = 0; c < 128; c++) acc += zr[c] * wbL[c * 12 + hh];
    a[((size_t)hh * NN + i) * NN + j0 + r] = W_L * acc + mterm;
  }
}

// ---------------- Kernel 3: qk + point-attention + softmax ----------------
__global__ void k_attn(const float* __restrict__ q, const float* __restrict__ k,
                       const float* __restrict__ qp, const float* __restrict__ kp,
                       const float* __restrict__ hws, float* __restrict__ a)
{
  const int i = blockIdx.x, h = blockIdx.y, t = threadIdx.x;
  __shared__ float qL[16], qpL[12];
  __shared__ float red[2][4];
  if (t < 16) qL[t] = q[i * 192 + h * 16 + t];
  else if (t >= 32 && t < 44) qpL[t - 32] = qp[((size_t)i * 48 + h * 4) * 3 + (t - 32)];
  __syncthreads();

  const float hwv = 0.13608276348f * log1pf(expf(hws[h]));
  const float W_C = 0.14433756730f;
  const size_t base = ((size_t)h * NN + i) * NN;

  float lg[2];
  for (int u = 0; u < 2; u++) {
    int j = t + u * 256;
    float acc = a[base + j];
    const float* kr = k + (size_t)j * 192 + h * 16;
    float dot = 0.f;
    for (int c = 0; c < 16; c++) dot += qL[c] * kr[c];
    const float* kpr = kp + ((size_t)j * 48 + h * 4) * 3;
    float d2 = 0.f;
    for (int p = 0; p < 4; p++) {
      float dx = qpL[p * 3 + 0] - kpr[p * 3 + 0];
      float dy = qpL[p * 3 + 1] - kpr[p * 3 + 1];
      float dz = qpL[p * 3 + 2] - kpr[p * 3 + 2];
      d2 += dx * dx + dy * dy + dz * dz;
    }
    lg[u] = acc + W_C * dot - 0.5f * hwv * d2;
  }

  float m = fmaxf(lg[0], lg[1]);
  for (int o = 1; o < 64; o <<= 1) m = fmaxf(m, __shfl_xor(m, o));
  if ((t & 63) == 0) red[0][t >> 6] = m;
  __syncthreads();
  m = fmaxf(fmaxf(red[0][0], red[0][1]), fmaxf(red[0][2], red[0][3]));
  float e0 = expf(lg[0] - m), e1 = expf(lg[1] - m);
  float sm = e0 + e1;
  for (int o = 1; o < 64; o <<= 1) sm += __shfl_xor(sm, o);
  if ((t & 63) == 0) red[1][t >> 6] = sm;
  __syncthreads();
  float inv = 1.0f / (red[1][0] + red[1][1] + red[1][2] + red[1][3]);
  a[base + t]       = e0 * inv;
  a[base + t + 256] = e1 * inv;
}

// ---------------- Kernel 4: o, o_pt (+inv rot, norm), o_pair -> cat ----------------
__global__ void k_out(const float* __restrict__ a, const float* __restrict__ v,
                      const float* __restrict__ vp, const float* __restrict__ z,
                      const float* __restrict__ rot, const float* __restrict__ trans,
                      float* __restrict__ cat)
{
  __shared__ float aL[12][513];
  __shared__ float optL[12][8][3];
  const int i = blockIdx.x, t = threadIdx.x;
  for (int u = t; u < 12 * 512; u += 512)
    aL[u >> 9][u & 511] = a[((size_t)(u >> 9) * NN + i) * NN + (u & 511)];
  __syncthreads();

  if (t < 192) {
    float acc = 0.f;
    const int h = t >> 4;
    for (int j = 0; j < 512; j++) acc += aL[h][j] * v[(size_t)j * 192 + t];
    cat[(size_t)i * CATd + t] = acc;
  } else if (t < 480) {
    int u = t - 192, h = u / 24;
    float acc = 0.f;
    for (int j = 0; j < 512; j++) acc += aL[h][j] * vp[(size_t)j * 288 + u];
    int pc = u % 24;
    optL[h][pc / 3][pc % 3] = acc;
  }
  __syncthreads();

  if (t < 96) {
    int h = t >> 3, p = t & 7;
    const float* Rm = rot + i * 9;
    const float* tr = trans + i * 3;
    float ox = optL[h][p][0] - tr[0];
    float oy = optL[h][p][1] - tr[1];
    float oz = optL[h][p][2] - tr[2];
    float rx = Rm[0] * ox + Rm[3] * oy + Rm[6] * oz;
    float ry = Rm[1] * ox + Rm[4] * oy + Rm[7] * oz;
    float rz = Rm[2] * ox + Rm[5] * oy + Rm[8] * oz;
    float nrm = sqrtf(rx * rx + ry * ry + rz * rz + 1e-8f);
    size_t b = (size_t)i * CATd;
    cat[b + 192 + t] = rx; cat[b + 288 + t] = ry;
    cat[b + 384 + t] = rz; cat[b + 480 + t] = nrm;
  }

  const int c = t & 127, hb = t >> 7;
  float a0 = 0.f, a1 = 0.f, a2 = 0.f;
  const float* zr = z + (size_t)i * 512 * 128 + c;
  for (int j = 0; j < 512; j++) {
    float zv = zr[(size_t)j * 128];
    a0 += aL[hb][j] * zv; a1 += aL[hb + 4][j] * zv; a2 += aL[hb + 8][j] * zv;
  }
  size_t b = (size_t)i * CATd + 576;
  cat[b + hb * 128 + c] = a0;
  cat[b + (hb + 4) * 128 + c] = a1;
  cat[b + (hb + 8) * 128 + c] = a2;
}

// ---------------- Kernel 5: out = cat @ w_out + b_out ----------------
__global__ void k_final(const float* __restrict__ cat, const float* __restrict__ w_out,
                        const float* __restrict__ b_out, float* __restrict__ out)
{
  __shared__ float catL[4 * CATd];
  const int i0 = blockIdx.x * 4, t = threadIdx.x;
  for (int u = t; u < 4 * CATd; u += 384) catL[u] = cat[(size_t)i0 * CATd + u];
  __syncthreads();
  float a0 = b_out[t], a1 = a0, a2 = a0, a3 = a0;
  for (int kk = 0; kk < CATd; kk++) {
    float w = w_out[kk * 384 + t];
    a0 += catL[kk] * w;
    a1 += catL[CATd + kk] * w;
    a2 += catL[2 * CATd + kk] * w;
    a3 += catL[3 * CATd + kk] * w;
  }
  out[(i0 + 0) * 384 + t] = a0;
  out[(i0 + 1) * 384 + t] = a1;
  out[(i0 + 2) * 384 + t] = a2;
  out[(i0 + 3) * 384 + t] = a3;
}

extern "C" void kernel_launch(void* const* d_in, const int* in_sizes, int n_in,
                              void* d_out, int out_size, void* d_ws, size_t ws_size,
                              hipStream_t stream) {
  const float* s      = (const float*)d_in[0];
  const float* z      = (const float*)d_in[1];
  const float* rot    = (const float*)d_in[2];
  const float* trans  = (const float*)d_in[3];
  const float* mask   = (const float*)d_in[4];
  const float* w_q    = (const float*)d_in[5];
  const float* b_q    = (const float*)d_in[6];
  const float* w_kv   = (const float*)d_in[7];
  const float* b_kv   = (const float*)d_in[8];
  const float* w_qp   = (const float*)d_in[9];
  const float* b_qp   = (const float*)d_in[10];
  const float* w_kvp  = (const float*)d_in[11];
  const float* b_kvp  = (const float*)d_in[12];
  const float* w_b    = (const float*)d_in[13];
  const float* b_b    = (const float*)d_in[14];
  const float* hws    = (const float*)d_in[15];
  const float* w_out  = (const float*)d_in[16];
  const float* b_out  = (const float*)d_in[17];
  float* out = (float*)d_out;

  float* ws  = (float*)d_ws;
  float* q   = ws;                 // 512*192
  float* k   = q  + 98304;
  float* v   = k  + 98304;
  float* qp  = v  + 98304;         // 512*48*3
  float* kp  = qp + 73728;
  float* vp  = kp + 73728;         // 512*96*3
  float* a   = vp + 147456;        // 12*512*512
  float* cat = a  + 3145728;       // 512*2112
  float* proj = a;                 // alias: proj[512*1152] consumed before k_bias writes a

  k_projgemm<<<dim3(16, 18), 256, 0, stream>>>(s, w_q, b_q, w_kv, b_kv,
                                               w_qp, b_qp, w_kvp, b_kvp, proj);
  k_rot<<<512, 256, 0, stream>>>(proj, rot, trans, q, k, v, qp, kp, vp);
  k_bias<<<4096, 256, 0, stream>>>(z, w_b, b_b, mask, a);
  k_attn<<<dim3(512, 12), 256, 0, stream>>>(q, k, qp, kp, hws, a);
  k_out<<<512, 512, 0, stream>>>(a, v, vp, z, rot, trans, cat);
  k_final<<<128, 384, 0, stream>>>(cat, w_out, b_out, out);
}

// Round 3
// 251.976 us; speedup vs baseline: 1.4845x; 1.2498x over previous
//
#include <hip/hip_runtime.h>
#include <math.h>

#define NN 512
#define CSd 384
#define Hh 12
#define CATd 2112
#define KF_CHUNK 264
#define KF_SPLIT 8

// ---------------- Kernel 1a: fused projection GEMM ----------------
__global__ void k_projgemm(const float* __restrict__ s,
                           const float* __restrict__ w_q, const float* __restrict__ b_q,
                           const float* __restrict__ w_kv, const float* __restrict__ b_kv,
                           const float* __restrict__ w_qp, const float* __restrict__ b_qp,
                           const float* __restrict__ w_kvp, const float* __restrict__ b_kvp,
                           float* __restrict__ proj)
{
  __shared__ float sT[384 * 40];
  const int t  = threadIdx.x;
  const int i0 = blockIdx.x * 32;
  const int c0 = blockIdx.y * 64;

  for (int u = t; u < 32 * 384; u += 256) {
    int row = u / 384, col = u % 384;
    sT[col * 40 + row] = s[(i0 + row) * CSd + col];
  }
  __syncthreads();

  const int c    = t & 63;
  const int rgrp = t >> 6;
  const int gc   = c0 + c;

  const float* wp;
  int stride;
  float bias;
  if (gc < 192)      { wp = w_q   + gc;         stride = 192; bias = b_q[gc]; }
  else if (gc < 576) { wp = w_kv  + (gc - 192); stride = 384; bias = b_kv[gc - 192]; }
  else if (gc < 720) { wp = w_qp  + (gc - 576); stride = 144; bias = b_qp[gc - 576]; }
  else               { wp = w_kvp + (gc - 720); stride = 432; bias = b_kvp[gc - 720]; }

  float acc[8];
#pragma unroll
  for (int j = 0; j < 8; j++) acc[j] = bias;

  const int r0 = rgrp * 8;
#pragma unroll 4
  for (int kk = 0; kk < 384; kk++) {
    float wv = *wp; wp += stride;
    const float4 a0 = *reinterpret_cast<const float4*>(&sT[kk * 40 + r0]);
    const float4 a1 = *reinterpret_cast<const float4*>(&sT[kk * 40 + r0 + 4]);
    acc[0] += a0.x * wv; acc[1] += a0.y * wv; acc[2] += a0.z * wv; acc[3] += a0.w * wv;
    acc[4] += a1.x * wv; acc[5] += a1.y * wv; acc[6] += a1.z * wv; acc[7] += a1.w * wv;
  }
#pragma unroll
  for (int j = 0; j < 8; j++)
    proj[(size_t)(i0 + r0 + j) * 1152 + gc] = acc[j];
}

// ---------------- Kernel 1b: scatter q/k/v + rotate points ----------------
__global__ void k_rot(const float* __restrict__ proj,
                      const float* __restrict__ rot, const float* __restrict__ trans,
                      float* __restrict__ q, float* __restrict__ k, float* __restrict__ v,
                      float* __restrict__ qp, float* __restrict__ kp, float* __restrict__ vp)
{
  __shared__ float ptsL[576];
  const int i = blockIdx.x, t = threadIdx.x;
  const float* pr = proj + (size_t)i * 1152;

  for (int u = t; u < 576; u += 256) ptsL[u] = pr[576 + u];

  for (int cI = t; cI < 576; cI += 256) {
    float pv = pr[cI];
    if (cI < 192) q[i * 192 + cI] = pv;
    else {
      int local = cI - 192, h = local >> 5, cc = local & 31;
      if (cc < 16) k[i * 192 + h * 16 + cc] = pv;
      else         v[i * 192 + h * 16 + cc - 16] = pv;
    }
  }
  __syncthreads();

  for (int p = t; p < 192; p += 256) {
    float x, y, zz;
    if (p < 48) { x = ptsL[p]; y = ptsL[48 + p]; zz = ptsL[96 + p]; }
    else { int idx = p - 48; x = ptsL[144 + idx]; y = ptsL[288 + idx]; zz = ptsL[432 + idx]; }
    const float* Rm = rot + i * 9;
    const float* tr = trans + i * 3;
    float rx = Rm[0] * x + Rm[1] * y + Rm[2] * zz + tr[0];
    float ry = Rm[3] * x + Rm[4] * y + Rm[5] * zz + tr[1];
    float rz = Rm[6] * x + Rm[7] * y + Rm[8] * zz + tr[2];
    if (p < 48) {
      float* d = qp + ((size_t)i * 48 + p) * 3;
      d[0] = rx; d[1] = ry; d[2] = rz;
    } else {
      int idx = p - 48, h = idx / 12, pp = idx % 12;
      if (pp < 4) { float* d = kp + ((size_t)i * 48 + h * 4 + pp) * 3; d[0] = rx; d[1] = ry; d[2] = rz; }
      else        { float* d = vp + ((size_t)i * 96 + h * 8 + pp - 4) * 3; d[0] = rx; d[1] = ry; d[2] = rz; }
    }
  }
}

// ---------------- Kernel 2: bias = z @ w_b, scaled + mask, into logits ----------------
__global__ void k_bias(const float* __restrict__ z, const float* __restrict__ w_b,
                       const float* __restrict__ b_b, const float* __restrict__ mask,
                       float* __restrict__ a)
{
  __shared__ float zL[64][129];
  __shared__ float wbL[128 * 12];
  const int t = threadIdx.x;
  const int row0 = blockIdx.x * 64;
  const int i = row0 >> 9;
  const int j0 = row0 & 511;

  for (int u = t; u < 1536; u += 256) wbL[u] = w_b[u];
  for (int u = t; u < 64 * 128; u += 256) zL[u >> 7][u & 127] = z[(size_t)row0 * 128 + u];
  __syncthreads();

  const int r = t & 63, hb = t >> 6;
  const float mi = mask[i], mj = mask[j0 + r];
  const float mterm = 100000.0f * (mi * mj - 1.0f);
  const float W_L = 0.57735026919f;
  const float* zr = zL[r];
  for (int hh = hb; hh < 12; hh += 4) {
    float acc = b_b[hh];
    for (int c = 0; c < 128; c++) acc += zr[c] * wbL[c * 12 + hh];
    a[((size_t)hh * NN + i) * NN + j0 + r] = W_L * acc + mterm;
  }
}

// ---------------- Kernel 3: qk + point-attention + softmax ----------------
__global__ void k_attn(const float* __restrict__ q, const float* __restrict__ k,
                       const float* __restrict__ qp, const float* __restrict__ kp,
                       const float* __restrict__ hws, float* __restrict__ a)
{
  const int i = blockIdx.x, h = blockIdx.y, t = threadIdx.x;
  __shared__ float qL[16], qpL[12];
  __shared__ float red[2][4];
  if (t < 16) qL[t] = q[i * 192 + h * 16 + t];
  else if (t >= 32 && t < 44) qpL[t - 32] = qp[((size_t)i * 48 + h * 4) * 3 + (t - 32)];
  __syncthreads();

  const float hwv = 0.13608276348f * log1pf(expf(hws[h]));
  const float W_C = 0.14433756730f;
  const size_t base = ((size_t)h * NN + i) * NN;

  float lg[2];
  for (int u = 0; u < 2; u++) {
    int j = t + u * 256;
    float acc = a[base + j];
    const float* kr = k + (size_t)j * 192 + h * 16;
    float dot = 0.f;
    for (int c = 0; c < 16; c++) dot += qL[c] * kr[c];
    const float* kpr = kp + ((size_t)j * 48 + h * 4) * 3;
    float d2 = 0.f;
    for (int p = 0; p < 4; p++) {
      float dx = qpL[p * 3 + 0] - kpr[p * 3 + 0];
      float dy = qpL[p * 3 + 1] - kpr[p * 3 + 1];
      float dz = qpL[p * 3 + 2] - kpr[p * 3 + 2];
      d2 += dx * dx + dy * dy + dz * dz;
    }
    lg[u] = acc + W_C * dot - 0.5f * hwv * d2;
  }

  float m = fmaxf(lg[0], lg[1]);
  for (int o = 1; o < 64; o <<= 1) m = fmaxf(m, __shfl_xor(m, o));
  if ((t & 63) == 0) red[0][t >> 6] = m;
  __syncthreads();
  m = fmaxf(fmaxf(red[0][0], red[0][1]), fmaxf(red[0][2], red[0][3]));
  float e0 = expf(lg[0] - m), e1 = expf(lg[1] - m);
  float sm = e0 + e1;
  for (int o = 1; o < 64; o <<= 1) sm += __shfl_xor(sm, o);
  if ((t & 63) == 0) red[1][t >> 6] = sm;
  __syncthreads();
  float inv = 1.0f / (red[1][0] + red[1][1] + red[1][2] + red[1][3]);
  a[base + t]       = e0 * inv;
  a[base + t + 256] = e1 * inv;
}

// ---------------- Kernel 4: o, o_pt (+inv rot, norm), o_pair -> cat ----------------
__global__ void k_out(const float* __restrict__ a, const float* __restrict__ v,
                      const float* __restrict__ vp, const float* __restrict__ z,
                      const float* __restrict__ rot, const float* __restrict__ trans,
                      float* __restrict__ cat)
{
  __shared__ float aL[12][513];
  __shared__ float optL[12][8][3];
  const int i = blockIdx.x, t = threadIdx.x;
  for (int u = t; u < 12 * 512; u += 512)
    aL[u >> 9][u & 511] = a[((size_t)(u >> 9) * NN + i) * NN + (u & 511)];
  __syncthreads();

  if (t < 192) {
    float acc = 0.f;
    const int h = t >> 4;
    for (int j = 0; j < 512; j++) acc += aL[h][j] * v[(size_t)j * 192 + t];
    cat[(size_t)i * CATd + t] = acc;
  } else if (t < 480) {
    int u = t - 192, h = u / 24;
    float acc = 0.f;
    for (int j = 0; j < 512; j++) acc += aL[h][j] * vp[(size_t)j * 288 + u];
    int pc = u % 24;
    optL[h][pc / 3][pc % 3] = acc;
  }
  __syncthreads();

  if (t < 96) {
    int h = t >> 3, p = t & 7;
    const float* Rm = rot + i * 9;
    const float* tr = trans + i * 3;
    float ox = optL[h][p][0] - tr[0];
    float oy = optL[h][p][1] - tr[1];
    float oz = optL[h][p][2] - tr[2];
    float rx = Rm[0] * ox + Rm[3] * oy + Rm[6] * oz;
    float ry = Rm[1] * ox + Rm[4] * oy + Rm[7] * oz;
    float rz = Rm[2] * ox + Rm[5] * oy + Rm[8] * oz;
    float nrm = sqrtf(rx * rx + ry * ry + rz * rz + 1e-8f);
    size_t b = (size_t)i * CATd;
    cat[b + 192 + t] = rx; cat[b + 288 + t] = ry;
    cat[b + 384 + t] = rz; cat[b + 480 + t] = nrm;
  }

  const int c = t & 127, hb = t >> 7;
  float a0 = 0.f, a1 = 0.f, a2 = 0.f;
  const float* zr = z + (size_t)i * 512 * 128 + c;
  for (int j = 0; j < 512; j++) {
    float zv = zr[(size_t)j * 128];
    a0 += aL[hb][j] * zv; a1 += aL[hb + 4][j] * zv; a2 += aL[hb + 8][j] * zv;
  }
  size_t b = (size_t)i * CATd + 576;
  cat[b + hb * 128 + c] = a0;
  cat[b + (hb + 4) * 128 + c] = a1;
  cat[b + (hb + 8) * 128 + c] = a2;
}

// ---------------- Kernel 5: split-K GEMM out = cat @ w_out ----------------
// grid (16, 6, 8), 256 threads; block = 32 rows x 64 cols x 264 k
__global__ void k_final(const float* __restrict__ cat, const float* __restrict__ w_out,
                        float* __restrict__ part)
{
  __shared__ float sT[KF_CHUNK * 36];   // 38 KB, transposed cat chunk
  const int t  = threadIdx.x;
  const int i0 = blockIdx.x * 32;
  const int c0 = blockIdx.y * 64;
  const int k0 = blockIdx.z * KF_CHUNK;

  for (int u = t; u < 32 * KF_CHUNK; u += 256) {
    int row = u / KF_CHUNK, kk = u % KF_CHUNK;
    sT[kk * 36 + row] = cat[(size_t)(i0 + row) * CATd + k0 + kk];
  }
  __syncthreads();

  const int c    = t & 63;
  const int rgrp = t >> 6;
  const int r0   = rgrp * 8;
  const int gc   = c0 + c;

  float acc[8];
#pragma unroll
  for (int j = 0; j < 8; j++) acc[j] = 0.f;

  const float* wp = w_out + (size_t)k0 * 384 + gc;
#pragma unroll 4
  for (int kk = 0; kk < KF_CHUNK; kk++) {
    float wv = wp[(size_t)kk * 384];
    const float4 a0 = *reinterpret_cast<const float4*>(&sT[kk * 36 + r0]);
    const float4 a1 = *reinterpret_cast<const float4*>(&sT[kk * 36 + r0 + 4]);
    acc[0] += a0.x * wv; acc[1] += a0.y * wv; acc[2] += a0.z * wv; acc[3] += a0.w * wv;
    acc[4] += a1.x * wv; acc[5] += a1.y * wv; acc[6] += a1.z * wv; acc[7] += a1.w * wv;
  }

  float* pb = part + (size_t)blockIdx.z * NN * 384;
#pragma unroll
  for (int j = 0; j < 8; j++)
    pb[(size_t)(i0 + r0 + j) * 384 + gc] = acc[j];
}

// ---------------- Kernel 6: reduce partials + bias ----------------
__global__ void k_reduce(const float* __restrict__ part, const float* __restrict__ b_out,
                         float* __restrict__ out)
{
  const int idx = blockIdx.x * 256 + threadIdx.x;   // 0 .. 512*384-1
  const int c = idx % 384;
  float acc = b_out[c];
#pragma unroll
  for (int ks = 0; ks < KF_SPLIT; ks++)
    acc += part[(size_t)ks * NN * 384 + idx];
  out[idx] = acc;
}

extern "C" void kernel_launch(void* const* d_in, const int* in_sizes, int n_in,
                              void* d_out, int out_size, void* d_ws, size_t ws_size,
                              hipStream_t stream) {
  const float* s      = (const float*)d_in[0];
  const float* z      = (const float*)d_in[1];
  const float* rot    = (const float*)d_in[2];
  const float* trans  = (const float*)d_in[3];
  const float* mask   = (const float*)d_in[4];
  const float* w_q    = (const float*)d_in[5];
  const float* b_q    = (const float*)d_in[6];
  const float* w_kv   = (const float*)d_in[7];
  const float* b_kv   = (const float*)d_in[8];
  const float* w_qp   = (const float*)d_in[9];
  const float* b_qp   = (const float*)d_in[10];
  const float* w_kvp  = (const float*)d_in[11];
  const float* b_kvp  = (const float*)d_in[12];
  const float* w_b    = (const float*)d_in[13];
  const float* b_b    = (const float*)d_in[14];
  const float* hws    = (const float*)d_in[15];
  const float* w_out  = (const float*)d_in[16];
  const float* b_out  = (const float*)d_in[17];
  float* out = (float*)d_out;

  float* ws  = (float*)d_ws;
  float* q   = ws;                 // 512*192
  float* k   = q  + 98304;
  float* v   = k  + 98304;
  float* qp  = v  + 98304;         // 512*48*3
  float* kp  = qp + 73728;
  float* vp  = kp + 73728;         // 512*96*3
  float* a   = vp + 147456;        // 12*512*512
  float* cat = a  + 3145728;       // 512*2112
  float* proj = a;                 // alias: consumed before k_bias writes a
  float* part = a;                 // alias: logits dead after k_out; 8*512*384 fits

  k_projgemm<<<dim3(16, 18), 256, 0, stream>>>(s, w_q, b_q, w_kv, b_kv,
                                               w_qp, b_qp, w_kvp, b_kvp, proj);
  k_rot<<<512, 256, 0, stream>>>(proj, rot, trans, q, k, v, qp, kp, vp);
  k_bias<<<4096, 256, 0, stream>>>(z, w_b, b_b, mask, a);
  k_attn<<<dim3(512, 12), 256, 0, stream>>>(q, k, qp, kp, hws, a);
  k_out<<<512, 512, 0, stream>>>(a, v, vp, z, rot, trans, cat);
  k_final<<<dim3(16, 6, KF_SPLIT), 256, 0, stream>>>(cat, w_out, part);
  k_reduce<<<768, 256, 0, stream>>>(part, b_out, out);
}

// Round 4
// 209.433 us; speedup vs baseline: 1.7860x; 1.2031x over previous
//
#include <hip/hip_runtime.h>
#include <math.h>

#define NN 512
#define CSd 384
#define Hh 12
#define CATd 2112
#define KF_CHUNK 264
#define KF_SPLIT 8

// ---------------- Kernel 1a: fused projection GEMM ----------------
__global__ void k_projgemm(const float* __restrict__ s,
                           const float* __restrict__ w_q, const float* __restrict__ b_q,
                           const float* __restrict__ w_kv, const float* __restrict__ b_kv,
                           const float* __restrict__ w_qp, const float* __restrict__ b_qp,
                           const float* __restrict__ w_kvp, const float* __restrict__ b_kvp,
                           float* __restrict__ proj)
{
  __shared__ float sT[384 * 40];
  const int t  = threadIdx.x;
  const int i0 = blockIdx.x * 32;
  const int c0 = blockIdx.y * 64;

  for (int u = t; u < 32 * 384; u += 256) {
    int row = u / 384, col = u % 384;
    sT[col * 40 + row] = s[(i0 + row) * CSd + col];
  }
  __syncthreads();

  const int c    = t & 63;
  const int rgrp = t >> 6;
  const int gc   = c0 + c;

  const float* wp;
  int stride;
  float bias;
  if (gc < 192)      { wp = w_q   + gc;         stride = 192; bias = b_q[gc]; }
  else if (gc < 576) { wp = w_kv  + (gc - 192); stride = 384; bias = b_kv[gc - 192]; }
  else if (gc < 720) { wp = w_qp  + (gc - 576); stride = 144; bias = b_qp[gc - 576]; }
  else               { wp = w_kvp + (gc - 720); stride = 432; bias = b_kvp[gc - 720]; }

  float acc[8];
#pragma unroll
  for (int j = 0; j < 8; j++) acc[j] = bias;

  const int r0 = rgrp * 8;
#pragma unroll 4
  for (int kk = 0; kk < 384; kk++) {
    float wv = *wp; wp += stride;
    const float4 a0 = *reinterpret_cast<const float4*>(&sT[kk * 40 + r0]);
    const float4 a1 = *reinterpret_cast<const float4*>(&sT[kk * 40 + r0 + 4]);
    acc[0] += a0.x * wv; acc[1] += a0.y * wv; acc[2] += a0.z * wv; acc[3] += a0.w * wv;
    acc[4] += a1.x * wv; acc[5] += a1.y * wv; acc[6] += a1.z * wv; acc[7] += a1.w * wv;
  }
#pragma unroll
  for (int j = 0; j < 8; j++)
    proj[(size_t)(i0 + r0 + j) * 1152 + gc] = acc[j];
}

// ---------------- Kernel 1b: scatter q/kT/v + rotate points (kpT j-major) ----------------
__global__ void k_rot(const float* __restrict__ proj,
                      const float* __restrict__ rot, const float* __restrict__ trans,
                      float* __restrict__ q, float* __restrict__ kT, float* __restrict__ v,
                      float* __restrict__ qp, float* __restrict__ kpT, float* __restrict__ vp)
{
  __shared__ float ptsL[576];
  const int i = blockIdx.x, t = threadIdx.x;
  const float* pr = proj + (size_t)i * 1152;

  for (int u = t; u < 576; u += 256) ptsL[u] = pr[576 + u];

  for (int cI = t; cI < 576; cI += 256) {
    float pv = pr[cI];
    if (cI < 192) q[i * 192 + cI] = pv;
    else {
      int local = cI - 192, h = local >> 5, cc = local & 31;
      if (cc < 16) kT[(size_t)(h * 16 + cc) * NN + i] = pv;      // j-major
      else         v[i * 192 + h * 16 + cc - 16] = pv;
    }
  }
  __syncthreads();

  for (int p = t; p < 192; p += 256) {
    float x, y, zz;
    if (p < 48) { x = ptsL[p]; y = ptsL[48 + p]; zz = ptsL[96 + p]; }
    else { int idx = p - 48; x = ptsL[144 + idx]; y = ptsL[288 + idx]; zz = ptsL[432 + idx]; }
    const float* Rm = rot + i * 9;
    const float* tr = trans + i * 3;
    float rx = Rm[0] * x + Rm[1] * y + Rm[2] * zz + tr[0];
    float ry = Rm[3] * x + Rm[4] * y + Rm[5] * zz + tr[1];
    float rz = Rm[6] * x + Rm[7] * y + Rm[8] * zz + tr[2];
    if (p < 48) {
      float* d = qp + ((size_t)i * 48 + p) * 3;
      d[0] = rx; d[1] = ry; d[2] = rz;
    } else {
      int idx = p - 48, h = idx / 12, pp = idx % 12;
      if (pp < 4) {                                // kpT[(h*4+pp)*3 + x][j]
        size_t rbase = (size_t)((h * 4 + pp) * 3) * NN + i;
        kpT[rbase] = rx; kpT[rbase + NN] = ry; kpT[rbase + 2 * NN] = rz;
      } else {
        float* d = vp + ((size_t)i * 96 + h * 8 + pp - 4) * 3;
        d[0] = rx; d[1] = ry; d[2] = rz;
      }
    }
  }
}

// ---------------- Kernel 2: bias = z @ w_b, scaled + mask, into logits ----------------
__global__ void k_bias(const float* __restrict__ z, const float* __restrict__ w_b,
                       const float* __restrict__ b_b, const float* __restrict__ mask,
                       float* __restrict__ a)
{
  __shared__ float zL[64][129];
  __shared__ float wbL[128 * 12];
  const int t = threadIdx.x;
  const int row0 = blockIdx.x * 64;
  const int i = row0 >> 9;
  const int j0 = row0 & 511;

  for (int u = t; u < 1536; u += 256) wbL[u] = w_b[u];
  for (int u = t; u < 64 * 128; u += 256) zL[u >> 7][u & 127] = z[(size_t)row0 * 128 + u];
  __syncthreads();

  const int r = t & 63, hb = t >> 6;
  const float mi = mask[i], mj = mask[j0 + r];
  const float mterm = 100000.0f * (mi * mj - 1.0f);
  const float W_L = 0.57735026919f;
  const float* zr = zL[r];
  for (int hh = hb; hh < 12; hh += 4) {
    float acc = b_b[hh];
    for (int c = 0; c < 128; c++) acc += zr[c] * wbL[c * 12 + hh];
    a[((size_t)hh * NN + i) * NN + j0 + r] = W_L * acc + mterm;
  }
}

// ---------------- Kernel 3: qk + point-attention + softmax (coalesced j-major) ----------------
// grid (512, 12), 256 threads; thread t handles j = 2t, 2t+1
__global__ void k_attn(const float* __restrict__ q, const float* __restrict__ kT,
                       const float* __restrict__ qp, const float* __restrict__ kpT,
                       const float* __restrict__ hws, float* __restrict__ a)
{
  const int i = blockIdx.x, h = blockIdx.y, t = threadIdx.x;
  __shared__ float qL[16], qpL[12];
  __shared__ float red[2][4];
  if (t < 16) qL[t] = q[i * 192 + h * 16 + t];
  else if (t >= 32 && t < 44) qpL[t - 32] = qp[(size_t)i * 144 + h * 12 + (t - 32)];
  __syncthreads();

  const float hwv = 0.13608276348f * log1pf(expf(hws[h]));
  const float W_C = 0.14433756730f;
  const size_t base = ((size_t)h * NN + i) * NN;
  const int j = t * 2;

  float2 lg = *reinterpret_cast<const float2*>(&a[base + j]);

  float dx = 0.f, dy = 0.f;
#pragma unroll
  for (int c = 0; c < 16; c++) {
    float2 kv = *reinterpret_cast<const float2*>(&kT[(size_t)((h << 4) + c) * NN + j]);
    dx += qL[c] * kv.x; dy += qL[c] * kv.y;
  }
  float s2x = 0.f, s2y = 0.f;
#pragma unroll
  for (int pc = 0; pc < 12; pc++) {
    float2 kv = *reinterpret_cast<const float2*>(&kpT[(size_t)(h * 12 + pc) * NN + j]);
    float qv = qpL[pc];
    float ddx = qv - kv.x, ddy = qv - kv.y;
    s2x += ddx * ddx; s2y += ddy * ddy;
  }
  lg.x += W_C * dx - 0.5f * hwv * s2x;
  lg.y += W_C * dy - 0.5f * hwv * s2y;

  float m = fmaxf(lg.x, lg.y);
  for (int o = 1; o < 64; o <<= 1) m = fmaxf(m, __shfl_xor(m, o));
  if ((t & 63) == 0) red[0][t >> 6] = m;
  __syncthreads();
  m = fmaxf(fmaxf(red[0][0], red[0][1]), fmaxf(red[0][2], red[0][3]));
  float e0 = expf(lg.x - m), e1 = expf(lg.y - m);
  float sm = e0 + e1;
  for (int o = 1; o < 64; o <<= 1) sm += __shfl_xor(sm, o);
  if ((t & 63) == 0) red[1][t >> 6] = sm;
  __syncthreads();
  float inv = 1.0f / (red[1][0] + red[1][1] + red[1][2] + red[1][3]);
  float2 res = make_float2(e0 * inv, e1 * inv);
  *reinterpret_cast<float2*>(&a[base + j]) = res;
}

// ---------------- Kernel 4: o, o_pt (+inv rot, norm), o_pair -> cat ----------------
__global__ void k_out(const float* __restrict__ a, const float* __restrict__ v,
                      const float* __restrict__ vp, const float* __restrict__ z,
                      const float* __restrict__ rot, const float* __restrict__ trans,
                      float* __restrict__ cat)
{
  __shared__ float aL[12][513];
  __shared__ float optL[12][8][3];
  const int i = blockIdx.x, t = threadIdx.x;
  for (int u = t; u < 12 * 512; u += 512)
    aL[u >> 9][u & 511] = a[((size_t)(u >> 9) * NN + i) * NN + (u & 511)];
  __syncthreads();

  if (t < 192) {
    float acc = 0.f;
    const int h = t >> 4;
    for (int j = 0; j < 512; j++) acc += aL[h][j] * v[(size_t)j * 192 + t];
    cat[(size_t)i * CATd + t] = acc;
  } else if (t < 480) {
    int u = t - 192, h = u / 24;
    float acc = 0.f;
    for (int j = 0; j < 512; j++) acc += aL[h][j] * vp[(size_t)j * 288 + u];
    int pc = u % 24;
    optL[h][pc / 3][pc % 3] = acc;
  }
  __syncthreads();

  if (t < 96) {
    int h = t >> 3, p = t & 7;
    const float* Rm = rot + i * 9;
    const float* tr = trans + i * 3;
    float ox = optL[h][p][0] - tr[0];
    float oy = optL[h][p][1] - tr[1];
    float oz = optL[h][p][2] - tr[2];
    float rx = Rm[0] * ox + Rm[3] * oy + Rm[6] * oz;
    float ry = Rm[1] * ox + Rm[4] * oy + Rm[7] * oz;
    float rz = Rm[2] * ox + Rm[5] * oy + Rm[8] * oz;
    float nrm = sqrtf(rx * rx + ry * ry + rz * rz + 1e-8f);
    size_t b = (size_t)i * CATd;
    cat[b + 192 + t] = rx; cat[b + 288 + t] = ry;
    cat[b + 384 + t] = rz; cat[b + 480 + t] = nrm;
  }

  const int c = t & 127, hb = t >> 7;
  float a0 = 0.f, a1 = 0.f, a2 = 0.f;
  const float* zr = z + (size_t)i * 512 * 128 + c;
  for (int j = 0; j < 512; j++) {
    float zv = zr[(size_t)j * 128];
    a0 += aL[hb][j] * zv; a1 += aL[hb + 4][j] * zv; a2 += aL[hb + 8][j] * zv;
  }
  size_t b = (size_t)i * CATd + 576;
  cat[b + hb * 128 + c] = a0;
  cat[b + (hb + 4) * 128 + c] = a1;
  cat[b + (hb + 8) * 128 + c] = a2;
}

// ---------------- Kernel 5: split-K GEMM out = cat @ w_out ----------------
__global__ void k_final(const float* __restrict__ cat, const float* __restrict__ w_out,
                        float* __restrict__ part)
{
  __shared__ float sT[KF_CHUNK * 36];
  const int t  = threadIdx.x;
  const int i0 = blockIdx.x * 32;
  const int c0 = blockIdx.y * 64;
  const int k0 = blockIdx.z * KF_CHUNK;

  for (int u = t; u < 32 * KF_CHUNK; u += 256) {
    int row = u / KF_CHUNK, kk = u % KF_CHUNK;
    sT[kk * 36 + row] = cat[(size_t)(i0 + row) * CATd + k0 + kk];
  }
  __syncthreads();

  const int c    = t & 63;
  const int rgrp = t >> 6;
  const int r0   = rgrp * 8;
  const int gc   = c0 + c;

  float acc[8];
#pragma unroll
  for (int j = 0; j < 8; j++) acc[j] = 0.f;

  const float* wp = w_out + (size_t)k0 * 384 + gc;
#pragma unroll 4
  for (int kk = 0; kk < KF_CHUNK; kk++) {
    float wv = wp[(size_t)kk * 384];
    const float4 a0 = *reinterpret_cast<const float4*>(&sT[kk * 36 + r0]);
    const float4 a1 = *reinterpret_cast<const float4*>(&sT[kk * 36 + r0 + 4]);
    acc[0] += a0.x * wv; acc[1] += a0.y * wv; acc[2] += a0.z * wv; acc[3] += a0.w * wv;
    acc[4] += a1.x * wv; acc[5] += a1.y * wv; acc[6] += a1.z * wv; acc[7] += a1.w * wv;
  }

  float* pb = part + (size_t)blockIdx.z * NN * 384;
#pragma unroll
  for (int j = 0; j < 8; j++)
    pb[(size_t)(i0 + r0 + j) * 384 + gc] = acc[j];
}

// ---------------- Kernel 6: reduce partials + bias ----------------
__global__ void k_reduce(const float* __restrict__ part, const float* __restrict__ b_out,
                         float* __restrict__ out)
{
  const int idx = blockIdx.x * 256 + threadIdx.x;
  const int c = idx % 384;
  float acc = b_out[c];
#pragma unroll
  for (int ks = 0; ks < KF_SPLIT; ks++)
    acc += part[(size_t)ks * NN * 384 + idx];
  out[idx] = acc;
}

extern "C" void kernel_launch(void* const* d_in, const int* in_sizes, int n_in,
                              void* d_out, int out_size, void* d_ws, size_t ws_size,
                              hipStream_t stream) {
  const float* s      = (const float*)d_in[0];
  const float* z      = (const float*)d_in[1];
  const float* rot    = (const float*)d_in[2];
  const float* trans  = (const float*)d_in[3];
  const float* mask   = (const float*)d_in[4];
  const float* w_q    = (const float*)d_in[5];
  const float* b_q    = (const float*)d_in[6];
  const float* w_kv   = (const float*)d_in[7];
  const float* b_kv   = (const float*)d_in[8];
  const float* w_qp   = (const float*)d_in[9];
  const float* b_qp   = (const float*)d_in[10];
  const float* w_kvp  = (const float*)d_in[11];
  const float* b_kvp  = (const float*)d_in[12];
  const float* w_b    = (const float*)d_in[13];
  const float* b_b    = (const float*)d_in[14];
  const float* hws    = (const float*)d_in[15];
  const float* w_out  = (const float*)d_in[16];
  const float* b_out  = (const float*)d_in[17];
  float* out = (float*)d_out;

  float* ws  = (float*)d_ws;
  float* q   = ws;                 // 512*192
  float* kT  = q  + 98304;         // [192][512] j-major
  float* v   = kT + 98304;
  float* qp  = v  + 98304;         // 512*48*3
  float* kpT = qp + 73728;         // [144][512] j-major
  float* vp  = kpT + 73728;        // 512*96*3
  float* a   = vp + 147456;        // 12*512*512
  float* cat = a  + 3145728;       // 512*2112
  float* proj = a;                 // alias: consumed before k_bias writes a
  float* part = a;                 // alias: logits dead after k_out

  k_projgemm<<<dim3(16, 18), 256, 0, stream>>>(s, w_q, b_q, w_kv, b_kv,
                                               w_qp, b_qp, w_kvp, b_kvp, proj);
  k_rot<<<512, 256, 0, stream>>>(proj, rot, trans, q, kT, v, qp, kpT, vp);
  k_bias<<<4096, 256, 0, stream>>>(z, w_b, b_b, mask, a);
  k_attn<<<dim3(512, 12), 256, 0, stream>>>(q, kT, qp, kpT, hws, a);
  k_out<<<512, 512, 0, stream>>>(a, v, vp, z, rot, trans, cat);
  k_final<<<dim3(16, 6, KF_SPLIT), 256, 0, stream>>>(cat, w_out, part);
  k_reduce<<<768, 256, 0, stream>>>(part, b_out, out);
}

// Round 5
// 199.827 us; speedup vs baseline: 1.8719x; 1.0481x over previous
//
#include <hip/hip_runtime.h>
#include <math.h>

#define NN 512
#define CSd 384
#define Hh 12
#define CATd 2112
#define KF_CHUNK 264
#define KF_SPLIT 8

// ---------------- Kernel 1a: fused projection GEMM ----------------
__global__ void k_projgemm(const float* __restrict__ s,
                           const float* __restrict__ w_q, const float* __restrict__ b_q,
                           const float* __restrict__ w_kv, const float* __restrict__ b_kv,
                           const float* __restrict__ w_qp, const float* __restrict__ b_qp,
                           const float* __restrict__ w_kvp, const float* __restrict__ b_kvp,
                           float* __restrict__ proj)
{
  __shared__ float sT[384 * 40];
  const int t  = threadIdx.x;
  const int i0 = blockIdx.x * 32;
  const int c0 = blockIdx.y * 64;

  for (int u = t; u < 32 * 384; u += 256) {
    int row = u / 384, col = u % 384;
    sT[col * 40 + row] = s[(i0 + row) * CSd + col];
  }
  __syncthreads();

  const int c    = t & 63;
  const int rgrp = t >> 6;
  const int gc   = c0 + c;

  const float* wp;
  int stride;
  float bias;
  if (gc < 192)      { wp = w_q   + gc;         stride = 192; bias = b_q[gc]; }
  else if (gc < 576) { wp = w_kv  + (gc - 192); stride = 384; bias = b_kv[gc - 192]; }
  else if (gc < 720) { wp = w_qp  + (gc - 576); stride = 144; bias = b_qp[gc - 576]; }
  else               { wp = w_kvp + (gc - 720); stride = 432; bias = b_kvp[gc - 720]; }

  float acc[8];
#pragma unroll
  for (int j = 0; j < 8; j++) acc[j] = bias;

  const int r0 = rgrp * 8;
#pragma unroll 4
  for (int kk = 0; kk < 384; kk++) {
    float wv = *wp; wp += stride;
    const float4 a0 = *reinterpret_cast<const float4*>(&sT[kk * 40 + r0]);
    const float4 a1 = *reinterpret_cast<const float4*>(&sT[kk * 40 + r0 + 4]);
    acc[0] += a0.x * wv; acc[1] += a0.y * wv; acc[2] += a0.z * wv; acc[3] += a0.w * wv;
    acc[4] += a1.x * wv; acc[5] += a1.y * wv; acc[6] += a1.z * wv; acc[7] += a1.w * wv;
  }
#pragma unroll
  for (int j = 0; j < 8; j++)
    proj[(size_t)(i0 + r0 + j) * 1152 + gc] = acc[j];
}

// ---------------- Kernel 1b: scatter q/kT/v + rotate points (kpT j-major) ----------------
__global__ void k_rot(const float* __restrict__ proj,
                      const float* __restrict__ rot, const float* __restrict__ trans,
                      float* __restrict__ q, float* __restrict__ kT, float* __restrict__ v,
                      float* __restrict__ qp, float* __restrict__ kpT, float* __restrict__ vp)
{
  __shared__ float ptsL[576];
  const int i = blockIdx.x, t = threadIdx.x;
  const float* pr = proj + (size_t)i * 1152;

  for (int u = t; u < 576; u += 256) ptsL[u] = pr[576 + u];

  for (int cI = t; cI < 576; cI += 256) {
    float pv = pr[cI];
    if (cI < 192) q[i * 192 + cI] = pv;
    else {
      int local = cI - 192, h = local >> 5, cc = local & 31;
      if (cc < 16) kT[(size_t)(h * 16 + cc) * NN + i] = pv;
      else         v[i * 192 + h * 16 + cc - 16] = pv;
    }
  }
  __syncthreads();

  for (int p = t; p < 192; p += 256) {
    float x, y, zz;
    if (p < 48) { x = ptsL[p]; y = ptsL[48 + p]; zz = ptsL[96 + p]; }
    else { int idx = p - 48; x = ptsL[144 + idx]; y = ptsL[288 + idx]; zz = ptsL[432 + idx]; }
    const float* Rm = rot + i * 9;
    const float* tr = trans + i * 3;
    float rx = Rm[0] * x + Rm[1] * y + Rm[2] * zz + tr[0];
    float ry = Rm[3] * x + Rm[4] * y + Rm[5] * zz + tr[1];
    float rz = Rm[6] * x + Rm[7] * y + Rm[8] * zz + tr[2];
    if (p < 48) {
      float* d = qp + ((size_t)i * 48 + p) * 3;
      d[0] = rx; d[1] = ry; d[2] = rz;
    } else {
      int idx = p - 48, h = idx / 12, pp = idx % 12;
      if (pp < 4) {
        size_t rbase = (size_t)((h * 4 + pp) * 3) * NN + i;
        kpT[rbase] = rx; kpT[rbase + NN] = ry; kpT[rbase + 2 * NN] = rz;
      } else {
        float* d = vp + ((size_t)i * 96 + h * 8 + pp - 4) * 3;
        d[0] = rx; d[1] = ry; d[2] = rz;
      }
    }
  }
}

// ---------------- Kernel 2: bias = z @ w_b (register-cached c-split) ----------------
// grid 4096 (64 j-rows of one i each), 256 threads: (r = t&63, cq = t>>6)
__global__ void k_bias(const float* __restrict__ z, const float* __restrict__ w_b,
                       const float* __restrict__ b_b, const float* __restrict__ mask,
                       float* __restrict__ a)
{
  __shared__ float zL[64 * 132];      // row stride 132 floats (16B-aligned)
  __shared__ float wT[12 * 128];      // w_b transposed [h][c]
  __shared__ float red[4][64][13];    // partial dots, pad 13
  const int t = threadIdx.x;
  const int row0 = blockIdx.x * 64;
  const int i = row0 >> 9;
  const int j0 = row0 & 511;

  for (int u = t; u < 1536; u += 256) {
    int h = u >> 7, c = u & 127;
    wT[u] = w_b[c * 12 + h];
  }
  const float4* z4 = reinterpret_cast<const float4*>(z + (size_t)row0 * 128);
  for (int u = t; u < 64 * 32; u += 256) {
    int r = u >> 5, c4 = u & 31;
    *reinterpret_cast<float4*>(&zL[r * 132 + c4 * 4]) = z4[u];
  }
  __syncthreads();

  const int r = t & 63, cq = t >> 6;
  float4 zr[8];
#pragma unroll
  for (int i4 = 0; i4 < 8; i4++)
    zr[i4] = *reinterpret_cast<const float4*>(&zL[r * 132 + cq * 32 + i4 * 4]);

  float acc[12];
#pragma unroll
  for (int h = 0; h < 12; h++) {
    float sv = 0.f;
#pragma unroll
    for (int i4 = 0; i4 < 8; i4++) {
      const float4 w = *reinterpret_cast<const float4*>(&wT[h * 128 + cq * 32 + i4 * 4]);
      sv += zr[i4].x * w.x + zr[i4].y * w.y + zr[i4].z * w.z + zr[i4].w * w.w;
    }
    acc[h] = sv;
  }
#pragma unroll
  for (int h = 0; h < 12; h++) red[cq][r][h] = acc[h];
  __syncthreads();

  const int rr = t & 63, hg = t >> 6;
  const float mi = mask[i], mj = mask[j0 + rr];
  const float mterm = 100000.0f * (mi * mj - 1.0f);
  const float W_L = 0.57735026919f;
#pragma unroll
  for (int h = hg * 3; h < hg * 3 + 3; h++) {
    float sv = b_b[h] + red[0][rr][h] + red[1][rr][h] + red[2][rr][h] + red[3][rr][h];
    a[((size_t)h * NN + i) * NN + j0 + rr] = W_L * sv + mterm;
  }
}

// ---------------- Kernel 3: qk + point-attention + softmax (coalesced j-major) ----------------
__global__ void k_attn(const float* __restrict__ q, const float* __restrict__ kT,
                       const float* __restrict__ qp, const float* __restrict__ kpT,
                       const float* __restrict__ hws, float* __restrict__ a)
{
  const int i = blockIdx.x, h = blockIdx.y, t = threadIdx.x;
  __shared__ float qL[16], qpL[12];
  __shared__ float red[2][4];
  if (t < 16) qL[t] = q[i * 192 + h * 16 + t];
  else if (t >= 32 && t < 44) qpL[t - 32] = qp[(size_t)i * 144 + h * 12 + (t - 32)];
  __syncthreads();

  const float hwv = 0.13608276348f * log1pf(expf(hws[h]));
  const float W_C = 0.14433756730f;
  const size_t base = ((size_t)h * NN + i) * NN;
  const int j = t * 2;

  float2 lg = *reinterpret_cast<const float2*>(&a[base + j]);

  float dx = 0.f, dy = 0.f;
#pragma unroll
  for (int c = 0; c < 16; c++) {
    float2 kv = *reinterpret_cast<const float2*>(&kT[(size_t)((h << 4) + c) * NN + j]);
    dx += qL[c] * kv.x; dy += qL[c] * kv.y;
  }
  float s2x = 0.f, s2y = 0.f;
#pragma unroll
  for (int pc = 0; pc < 12; pc++) {
    float2 kv = *reinterpret_cast<const float2*>(&kpT[(size_t)(h * 12 + pc) * NN + j]);
    float qv = qpL[pc];
    float ddx = qv - kv.x, ddy = qv - kv.y;
    s2x += ddx * ddx; s2y += ddy * ddy;
  }
  lg.x += W_C * dx - 0.5f * hwv * s2x;
  lg.y += W_C * dy - 0.5f * hwv * s2y;

  float m = fmaxf(lg.x, lg.y);
  for (int o = 1; o < 64; o <<= 1) m = fmaxf(m, __shfl_xor(m, o));
  if ((t & 63) == 0) red[0][t >> 6] = m;
  __syncthreads();
  m = fmaxf(fmaxf(red[0][0], red[0][1]), fmaxf(red[0][2], red[0][3]));
  float e0 = expf(lg.x - m), e1 = expf(lg.y - m);
  float sm = e0 + e1;
  for (int o = 1; o < 64; o <<= 1) sm += __shfl_xor(sm, o);
  if ((t & 63) == 0) red[1][t >> 6] = sm;
  __syncthreads();
  float inv = 1.0f / (red[1][0] + red[1][1] + red[1][2] + red[1][3]);
  float2 res = make_float2(e0 * inv, e1 * inv);
  *reinterpret_cast<float2*>(&a[base + j]) = res;
}

// ---------------- Kernel 4: o, o_pt (+inv rot, norm), o_pair -> cat ----------------
// grid 512 (one i), 512 threads. o_pair is j-quartered so z is read once.
__global__ void k_out(const float* __restrict__ a, const float* __restrict__ v,
                      const float* __restrict__ vp, const float* __restrict__ z,
                      const float* __restrict__ rot, const float* __restrict__ trans,
                      float* __restrict__ cat)
{
  __shared__ float aL[12][513];
  __shared__ float optL[12][8][3];
  __shared__ float redp[4][12][129];   // o_pair partials per j-quarter
  const int i = blockIdx.x, t = threadIdx.x;
  for (int u = t; u < 12 * 512; u += 512)
    aL[u >> 9][u & 511] = a[((size_t)(u >> 9) * NN + i) * NN + (u & 511)];
  __syncthreads();

  // phase 2: o_pair partials; thread (c = t&127, jq = t>>7)
  {
    const int c = t & 127, jq = t >> 7;
    float pa[12];
#pragma unroll
    for (int h = 0; h < 12; h++) pa[h] = 0.f;
    const float* zr = z + (size_t)i * 65536 + c;
    const int jend = jq * 128 + 128;
    for (int j = jq * 128; j < jend; j++) {
      float zv = zr[(size_t)j * 128];
#pragma unroll
      for (int h = 0; h < 12; h++) pa[h] += aL[h][j] * zv;
    }
#pragma unroll
    for (int h = 0; h < 12; h++) redp[jq][h][c] = pa[h];
  }
  __syncthreads();

  // phase 3: o (t<192) and o_pt (192<=t<480)
  if (t < 192) {
    float acc = 0.f;
    const int h = t >> 4;
    for (int j = 0; j < 512; j++) acc += aL[h][j] * v[(size_t)j * 192 + t];
    cat[(size_t)i * CATd + t] = acc;
  } else if (t < 480) {
    int u = t - 192, h = u / 24;
    float acc = 0.f;
    for (int j = 0; j < 512; j++) acc += aL[h][j] * vp[(size_t)j * 288 + u];
    int pc = u % 24;
    optL[h][pc / 3][pc % 3] = acc;
  }
  __syncthreads();

  // phase 4a: inverse rotation + norm
  if (t < 96) {
    int h = t >> 3, p = t & 7;
    const float* Rm = rot + i * 9;
    const float* tr = trans + i * 3;
    float ox = optL[h][p][0] - tr[0];
    float oy = optL[h][p][1] - tr[1];
    float oz = optL[h][p][2] - tr[2];
    float rx = Rm[0] * ox + Rm[3] * oy + Rm[6] * oz;
    float ry = Rm[1] * ox + Rm[4] * oy + Rm[7] * oz;
    float rz = Rm[2] * ox + Rm[5] * oy + Rm[8] * oz;
    float nrm = sqrtf(rx * rx + ry * ry + rz * rz + 1e-8f);
    size_t b = (size_t)i * CATd;
    cat[b + 192 + t] = rx; cat[b + 288 + t] = ry;
    cat[b + 384 + t] = rz; cat[b + 480 + t] = nrm;
  }

  // phase 4b: o_pair reduce, 1536 outputs, 3 per thread (coalesced)
#pragma unroll
  for (int kph = 0; kph < 3; kph++) {
    int e = t + kph * 512;
    int h = e >> 7, c = e & 127;
    float sv = redp[0][h][c] + redp[1][h][c] + redp[2][h][c] + redp[3][h][c];
    cat[(size_t)i * CATd + 576 + e] = sv;
  }
}

// ---------------- Kernel 5: split-K GEMM out = cat @ w_out ----------------
__global__ void k_final(const float* __restrict__ cat, const float* __restrict__ w_out,
                        float* __restrict__ part)
{
  __shared__ float sT[KF_CHUNK * 36];
  const int t  = threadIdx.x;
  const int i0 = blockIdx.x * 32;
  const int c0 = blockIdx.y * 64;
  const int k0 = blockIdx.z * KF_CHUNK;

  for (int u = t; u < 32 * KF_CHUNK; u += 256) {
    int row = u / KF_CHUNK, kk = u % KF_CHUNK;
    sT[kk * 36 + row] = cat[(size_t)(i0 + row) * CATd + k0 + kk];
  }
  __syncthreads();

  const int c    = t & 63;
  const int rgrp = t >> 6;
  const int r0   = rgrp * 8;
  const int gc   = c0 + c;

  float acc[8];
#pragma unroll
  for (int j = 0; j < 8; j++) acc[j] = 0.f;

  const float* wp = w_out + (size_t)k0 * 384 + gc;
#pragma unroll 4
  for (int kk = 0; kk < KF_CHUNK; kk++) {
    float wv = wp[(size_t)kk * 384];
    const float4 a0 = *reinterpret_cast<const float4*>(&sT[kk * 36 + r0]);
    const float4 a1 = *reinterpret_cast<const float4*>(&sT[kk * 36 + r0 + 4]);
    acc[0] += a0.x * wv; acc[1] += a0.y * wv; acc[2] += a0.z * wv; acc[3] += a0.w * wv;
    acc[4] += a1.x * wv; acc[5] += a1.y * wv; acc[6] += a1.z * wv; acc[7] += a1.w * wv;
  }

  float* pb = part + (size_t)blockIdx.z * NN * 384;
#pragma unroll
  for (int j = 0; j < 8; j++)
    pb[(size_t)(i0 + r0 + j) * 384 + gc] = acc[j];
}

// ---------------- Kernel 6: reduce partials + bias ----------------
__global__ void k_reduce(const float* __restrict__ part, const float* __restrict__ b_out,
                         float* __restrict__ out)
{
  const int idx = blockIdx.x * 256 + threadIdx.x;
  const int c = idx % 384;
  float acc = b_out[c];
#pragma unroll
  for (int ks = 0; ks < KF_SPLIT; ks++)
    acc += part[(size_t)ks * NN * 384 + idx];
  out[idx] = acc;
}

extern "C" void kernel_launch(void* const* d_in, const int* in_sizes, int n_in,
                              void* d_out, int out_size, void* d_ws, size_t ws_size,
                              hipStream_t stream) {
  const float* s      = (const float*)d_in[0];
  const float* z      = (const float*)d_in[1];
  const float* rot    = (const float*)d_in[2];
  const float* trans  = (const float*)d_in[3];
  const float* mask   = (const float*)d_in[4];
  const float* w_q    = (const float*)d_in[5];
  const float* b_q    = (const float*)d_in[6];
  const float* w_kv   = (const float*)d_in[7];
  const float* b_kv   = (const float*)d_in[8];
  const float* w_qp   = (const float*)d_in[9];
  const float* b_qp   = (const float*)d_in[10];
  const float* w_kvp  = (const float*)d_in[11];
  const float* b_kvp  = (const float*)d_in[12];
  const float* w_b    = (const float*)d_in[13];
  const float* b_b    = (const float*)d_in[14];
  const float* hws    = (const float*)d_in[15];
  const float* w_out  = (const float*)d_in[16];
  const float* b_out  = (const float*)d_in[17];
  float* out = (float*)d_out;

  float* ws  = (float*)d_ws;
  float* q   = ws;                 // 512*192
  float* kT  = q  + 98304;         // [192][512] j-major
  float* v   = kT + 98304;
  float* qp  = v  + 98304;         // 512*48*3
  float* kpT = qp + 73728;         // [144][512] j-major
  float* vp  = kpT + 73728;        // 512*96*3
  float* a   = vp + 147456;        // 12*512*512
  float* cat = a  + 3145728;       // 512*2112
  float* proj = a;                 // alias: consumed before k_bias writes a
  float* part = a;                 // alias: logits dead after k_out

  k_projgemm<<<dim3(16, 18), 256, 0, stream>>>(s, w_q, b_q, w_kv, b_kv,
                                               w_qp, b_qp, w_kvp, b_kvp, proj);
  k_rot<<<512, 256, 0, stream>>>(proj, rot, trans, q, kT, v, qp, kpT, vp);
  k_bias<<<4096, 256, 0, stream>>>(z, w_b, b_b, mask, a);
  k_attn<<<dim3(512, 12), 256, 0, stream>>>(q, kT, qp, kpT, hws, a);
  k_out<<<512, 512, 0, stream>>>(a, v, vp, z, rot, trans, cat);
  k_final<<<dim3(16, 6, KF_SPLIT), 256, 0, stream>>>(cat, w_out, part);
  k_reduce<<<768, 256, 0, stream>>>(part, b_out, out);
}